// Round 2
// baseline (630.098 us; speedup 1.0000x reference)
//
#include <hip/hip_runtime.h>
#include <hip/hip_bf16.h>
#include <cstdint>
#include <cstddef>

#define DM   1024
#define VG   2048
#define QKD  128
#define NB   8
#define SEQ  2048
#define NH   4224      // 2*VG + QKD
#define MTOT 16384     // NB*SEQ
#define CH   1024      // attention query-row chunk per batch (P overlays xb)

typedef __bf16 bf16;
typedef __attribute__((ext_vector_type(8))) __bf16 bf16x8;
typedef __attribute__((ext_vector_type(4))) float f32x4;

__device__ __forceinline__ void gload16(void* lds, const void* g) {
  __builtin_amdgcn_global_load_lds(
      (const __attribute__((address_space(1))) uint32_t*)g,
      (__attribute__((address_space(3))) uint32_t*)lds, 16, 0, 0);
}

// Computes a 128x128 C tile: C = A(128 x K) * Bt(128 x K)^T.
// Ab/Bb point at the tile origin rows; row stride == K for both.
// 256 threads = 4 waves in 2x2 grid; each wave owns a 64x64 subtile as
// 4x4 fragments of 16x16, K-step 64 (2 MFMA K-slices of 32).
__device__ __forceinline__ void gemm_core(const bf16* __restrict__ Ab,
                                          const bf16* __restrict__ Bb,
                                          int K, f32x4 acc[4][4]) {
  __shared__ alignas(16) bf16 lsA[128 * 64];
  __shared__ alignas(16) bf16 lsB[128 * 64];
  const int t    = threadIdx.x;
  const int lane = t & 63;
  const int wid  = t >> 6;
  const int wr   = wid >> 1;
  const int wc   = wid & 1;
  const int lr   = lane & 15;         // fragment row (A) / col (B)
  const int kg   = (lane >> 4) << 3;  // k-offset within 32: 0,8,16,24

#pragma unroll
  for (int m = 0; m < 4; ++m)
#pragma unroll
    for (int n = 0; n < 4; ++n)
      acc[m][n] = f32x4{0.f, 0.f, 0.f, 0.f};

  for (int k0 = 0; k0 < K; k0 += 64) {
    // stage A,B tiles (128x64 bf16 each) via async global->LDS, 16B/lane
#pragma unroll
    for (int i = 0; i < 4; ++i) {
      const int flat = i * 256 + t;       // 0..1023
      const int r = flat >> 3;            // 0..127
      const int c = (flat & 7) << 3;      // 0..56
      gload16(lsA + (size_t)flat * 8, Ab + (size_t)r * K + k0 + c);
      gload16(lsB + (size_t)flat * 8, Bb + (size_t)r * K + k0 + c);
    }
    __syncthreads();  // drains vmcnt before barrier -> tiles visible
#pragma unroll
    for (int kk = 0; kk < 64; kk += 32) {
      bf16x8 af[4], bfr[4];
#pragma unroll
      for (int m = 0; m < 4; ++m)
        af[m] = *(const bf16x8*)&lsA[(size_t)(wr * 64 + m * 16 + lr) * 64 + kk + kg];
#pragma unroll
      for (int n = 0; n < 4; ++n)
        bfr[n] = *(const bf16x8*)&lsB[(size_t)(wc * 64 + n * 16 + lr) * 64 + kk + kg];
#pragma unroll
      for (int m = 0; m < 4; ++m)
#pragma unroll
        for (int n = 0; n < 4; ++n)
          acc[m][n] = __builtin_amdgcn_mfma_f32_16x16x32_bf16(af[m], bfr[n], acc[m][n], 0, 0, 0);
    }
    __syncthreads();  // protect LDS from next iteration's staging
  }
}

// C/D fragment mapping (m89/m91-verified): row=(lane>>4)*4+j, col=lane&15
__device__ __forceinline__ int epi_lrow(int m, int j) {
  const int lane = threadIdx.x & 63;
  const int wr = (threadIdx.x >> 6) >> 1;
  return wr * 64 + m * 16 + ((lane >> 4) << 2) + j;
}
__device__ __forceinline__ int epi_lcol(int n) {
  const int lane = threadIdx.x & 63;
  const int wc = (threadIdx.x >> 6) & 1;
  return wc * 64 + n * 16 + (lane & 15);
}

// ---------------- conversion / transpose ----------------

__global__ __launch_bounds__(256)
void k_cvt(const float* __restrict__ in, bf16* __restrict__ out, int n8) {
  const int i = blockIdx.x * 256 + threadIdx.x;
  if (i >= n8) return;
  const float* p = in + (size_t)i * 8;
  bf16x8 o;
#pragma unroll
  for (int j = 0; j < 8; ++j) o[j] = (bf16)p[j];
  *(bf16x8*)(out + (size_t)i * 8) = o;
}

// in: R x C fp32 (row-major) -> out: C x R bf16
__global__ __launch_bounds__(256)
void k_transpose(const float* __restrict__ in, bf16* __restrict__ out, int R, int C) {
  __shared__ float tile[64][65];
  const int r0 = blockIdx.y * 64, c0 = blockIdx.x * 64;
  const int t = threadIdx.x;
#pragma unroll
  for (int i = 0; i < 16; ++i) {
    const int flat = i * 256 + t;
    const int r = flat >> 6, c = flat & 63;
    tile[r][c] = in[(size_t)(r0 + r) * C + (c0 + c)];
  }
  __syncthreads();
#pragma unroll
  for (int i = 0; i < 16; ++i) {
    const int flat = i * 256 + t;
    const int r = flat >> 6, c = flat & 63;
    out[(size_t)(c0 + r) * R + (r0 + c)] = (bf16)tile[c][r];
  }
}

// In-place per-batch transpose of a SEQ x SEQ bf16 matrix (tile-pair swap).
// grid (SEQ/64, SEQ/64, NB); blocks with bj < bi exit early.
__global__ __launch_bounds__(256)
void k_vtrans(bf16* __restrict__ a) {
  const int bi = blockIdx.y, bj = blockIdx.x;
  if (bj < bi) return;
  bf16* A = a + (size_t)blockIdx.z * SEQ * SEQ;
  __shared__ float t0[64][65];
  __shared__ float t1[64][65];
  const int r0 = bi * 64, c0 = bj * 64;
  const int t = threadIdx.x;
  const bool diag = (bi == bj);
#pragma unroll
  for (int i = 0; i < 16; ++i) {
    const int flat = i * 256 + t;
    const int r = flat >> 6, c = flat & 63;
    t0[r][c] = (float)A[(size_t)(r0 + r) * SEQ + (c0 + c)];
    if (!diag) t1[r][c] = (float)A[(size_t)(c0 + r) * SEQ + (r0 + c)];
  }
  __syncthreads();
#pragma unroll
  for (int i = 0; i < 16; ++i) {
    const int flat = i * 256 + t;
    const int r = flat >> 6, c = flat & 63;
    A[(size_t)(r0 + r) * SEQ + (c0 + c)] = (bf16)(diag ? t0[c][r] : t1[c][r]);
    if (!diag) A[(size_t)(c0 + r) * SEQ + (r0 + c)] = (bf16)t0[c][r];
  }
}

// ---------------- GEMM1: h = x@W_i + b_i ; SiLU ; split u/v/q/k ----------------

__global__ __launch_bounds__(256, 2)
void k_gemm1(const bf16* __restrict__ xb, const bf16* __restrict__ wibt,
             const float* __restrict__ b_i,
             const float* __restrict__ q_w, const float* __restrict__ q_b,
             const float* __restrict__ k_w, const float* __restrict__ k_b,
             bf16* __restrict__ u, bf16* __restrict__ v,
             bf16* __restrict__ q, bf16* __restrict__ k) {
  const int bm0 = blockIdx.y * 128;
  const int bn0 = blockIdx.x * 128;
  f32x4 acc[4][4];
  gemm_core(xb + (size_t)bm0 * DM, wibt + (size_t)bn0 * DM, DM, acc);
  const float rs = 0.08838834764831845f;  // 1/sqrt(128)
#pragma unroll
  for (int m = 0; m < 4; ++m)
#pragma unroll
    for (int n = 0; n < 4; ++n)
#pragma unroll
      for (int j = 0; j < 4; ++j) {
        const int row = bm0 + epi_lrow(m, j);
        const int col = bn0 + epi_lcol(n);
        const float h = acc[m][n][j] + b_i[col];
        const float s = h / (1.f + __expf(-h));  // silu
        if (col < VG) {
          u[(size_t)row * VG + col] = (bf16)s;
        } else if (col < 2 * VG) {
          v[(size_t)row * VG + (col - VG)] = (bf16)s;
        } else {
          const int c = col - 2 * VG;
          q[(size_t)row * QKD + c] = (bf16)((s * q_w[c] + q_b[c]) * rs);
          k[(size_t)row * QKD + c] = (bf16)(s * k_w[c] + k_b[c]);
        }
      }
}

// ---------------- S-chunk = q[m0:m0+CH] @ k^T (per batch) ----------------

__global__ __launch_bounds__(256, 2)
void k_gemmS(const bf16* __restrict__ q, const bf16* __restrict__ k,
             bf16* __restrict__ P, int m0) {
  const int b = blockIdx.z;
  const int bm0 = blockIdx.y * 128, bn0 = blockIdx.x * 128;
  f32x4 acc[4][4];
  gemm_core(q + ((size_t)b * SEQ + m0 + bm0) * QKD,
            k + ((size_t)b * SEQ + bn0) * QKD, QKD, acc);
  bf16* Pb = P + (size_t)b * CH * SEQ;
#pragma unroll
  for (int m = 0; m < 4; ++m)
#pragma unroll
    for (int n = 0; n < 4; ++n)
#pragma unroll
      for (int j = 0; j < 4; ++j)
        Pb[(size_t)(bm0 + epi_lrow(m, j)) * SEQ + (bn0 + epi_lcol(n))] =
            (bf16)acc[m][n][j];
}

// ---------------- row softmax over chunk (in place), key padding mask ----------------

__global__ __launch_bounds__(256)
void k_softmax(bf16* __restrict__ P, const int* __restrict__ mask) {
  const int row = blockIdx.x;       // 0..NB*CH-1
  const int b = row >> 10;          // row / CH
  const int t = threadIdx.x;
  bf16* srow = P + (size_t)row * SEQ;
  const int* mrow = mask + (size_t)b * SEQ;
  bf16x8 vv = *(const bf16x8*)(srow + t * 8);
  float f[8];
  float mx = -1e30f;
#pragma unroll
  for (int j = 0; j < 8; ++j) {
    const bool ok = mrow[t * 8 + j] != 0;
    f[j] = ok ? (float)vv[j] : -1e30f;
    mx = fmaxf(mx, f[j]);
  }
#pragma unroll
  for (int off = 32; off > 0; off >>= 1) mx = fmaxf(mx, __shfl_xor(mx, off));
  __shared__ float redm[4], reds[4];
  if ((t & 63) == 0) redm[t >> 6] = mx;
  __syncthreads();
  mx = fmaxf(fmaxf(redm[0], redm[1]), fmaxf(redm[2], redm[3]));
  float sum = 0.f;
#pragma unroll
  for (int j = 0; j < 8; ++j) {
    f[j] = (f[j] > -1e29f) ? __expf(f[j] - mx) : 0.f;
    sum += f[j];
  }
#pragma unroll
  for (int off = 32; off > 0; off >>= 1) sum += __shfl_xor(sum, off);
  if ((t & 63) == 0) reds[t >> 6] = sum;
  __syncthreads();
  sum = reds[0] + reds[1] + reds[2] + reds[3];
  const float inv = 1.f / sum;
#pragma unroll
  for (int j = 0; j < 8; ++j) vv[j] = (bf16)(f[j] * inv);
  *(bf16x8*)(srow + t * 8) = vv;
}

// ---------------- o = u .* (P @ v), written over u in place ----------------
// vT is the in-place-transposed v: per batch VG x SEQ (K-contiguous rows)

__global__ __launch_bounds__(256, 2)
void k_gemmO(const bf16* __restrict__ P, const bf16* __restrict__ vT,
             bf16* uo, int m0) {
  const int b = blockIdx.z;
  const int bm0 = blockIdx.y * 128, bn0 = blockIdx.x * 128;
  f32x4 acc[4][4];
  gemm_core(P + ((size_t)b * CH + bm0) * SEQ,
            vT + ((size_t)b * VG + bn0) * SEQ, SEQ, acc);
#pragma unroll
  for (int m = 0; m < 4; ++m)
#pragma unroll
    for (int n = 0; n < 4; ++n)
#pragma unroll
      for (int j = 0; j < 4; ++j) {
        const size_t idx =
            ((size_t)(b * SEQ + m0 + bm0 + epi_lrow(m, j))) * VG + bn0 + epi_lcol(n);
        uo[idx] = (bf16)(acc[m][n][j] * (float)uo[idx]);
      }
}

// ---------------- out = o @ W_o + b_o (fp32 out) ----------------

__global__ __launch_bounds__(256, 2)
void k_gemm2(const bf16* __restrict__ o, const bf16* __restrict__ wobt,
             const float* __restrict__ b_o, float* __restrict__ out) {
  const int bm0 = blockIdx.y * 128, bn0 = blockIdx.x * 128;
  f32x4 acc[4][4];
  gemm_core(o + (size_t)bm0 * VG, wobt + (size_t)bn0 * VG, VG, acc);
#pragma unroll
  for (int m = 0; m < 4; ++m)
#pragma unroll
    for (int n = 0; n < 4; ++n)
#pragma unroll
      for (int j = 0; j < 4; ++j)
        out[(size_t)(bm0 + epi_lrow(m, j)) * DM + bn0 + epi_lcol(n)] =
            acc[m][n][j] + b_o[bn0 + epi_lcol(n)];
}

// ---------------- launch ----------------
// Workspace plan (189.1 MB total; P-chunk overlays dead xb):
//   wobt 4.19MB | xb/P 33.55MB | wibt 8.65MB | qb 4.19MB | kb 4.19MB
//   | uo 67.1MB | v 67.1MB

extern "C" void kernel_launch(void* const* d_in, const int* in_sizes, int n_in,
                              void* d_out, int out_size, void* d_ws, size_t ws_size,
                              hipStream_t stream) {
  const float* x   = (const float*)d_in[0];
  const int*   pm  = (const int*)d_in[1];
  const float* W_i = (const float*)d_in[2];
  const float* b_i = (const float*)d_in[3];
  const float* q_w = (const float*)d_in[4];
  const float* q_b = (const float*)d_in[5];
  const float* k_w = (const float*)d_in[6];
  const float* k_b = (const float*)d_in[7];
  const float* W_o = (const float*)d_in[8];
  const float* b_o = (const float*)d_in[9];
  float* out = (float*)d_out;

  char* w = (char*)d_ws;
  bf16* wobt = (bf16*)w; w += (size_t)DM * VG * 2;     //  4.2 MB
  bf16* xb   = (bf16*)w; w += (size_t)MTOT * DM * 2;   // 33.6 MB (reused as P)
  bf16* wibt = (bf16*)w; w += (size_t)NH * DM * 2;     //  8.7 MB
  bf16* qb   = (bf16*)w; w += (size_t)MTOT * QKD * 2;  //  4.2 MB
  bf16* kb   = (bf16*)w; w += (size_t)MTOT * QKD * 2;  //  4.2 MB
  bf16* uo   = (bf16*)w; w += (size_t)MTOT * VG * 2;   // 67.1 MB (u, then o)
  bf16* vb   = (bf16*)w; w += (size_t)MTOT * VG * 2;   // 67.1 MB (v, then vT)
  bf16* Pc   = xb;                                     // P chunk overlays xb

  // x -> bf16
  k_cvt<<<dim3(MTOT * DM / 8 / 256), 256, 0, stream>>>(x, xb, MTOT * DM / 8);
  // W_i (DM x NH) -> (NH x DM) bf16 ; W_o (VG x DM) -> (DM x VG) bf16
  k_transpose<<<dim3(NH / 64, DM / 64), 256, 0, stream>>>(W_i, wibt, DM, NH);
  k_transpose<<<dim3(DM / 64, VG / 64), 256, 0, stream>>>(W_o, wobt, VG, DM);
  // GEMM1 + silu + split (xb dead afterwards)
  k_gemm1<<<dim3(NH / 128, MTOT / 128), 256, 0, stream>>>(
      xb, wibt, b_i, q_w, q_b, k_w, k_b, uo, vb, qb, kb);
  // v -> v^T in place (square per batch)
  k_vtrans<<<dim3(SEQ / 64, SEQ / 64, NB), 256, 0, stream>>>(vb);
  // attention in CH-row chunks; P overlays xb
  for (int c = 0; c < SEQ / CH; ++c) {
    const int m0 = c * CH;
    k_gemmS<<<dim3(SEQ / 128, CH / 128, NB), 256, 0, stream>>>(qb, kb, Pc, m0);
    k_softmax<<<dim3(NB * CH), 256, 0, stream>>>(Pc, pm);
    k_gemmO<<<dim3(VG / 128, CH / 128, NB), 256, 0, stream>>>(Pc, vb, uo, m0);
  }
  // out = o @ W_o + b_o
  k_gemm2<<<dim3(DM / 128, MTOT / 128), 256, 0, stream>>>(uo, wobt, b_o, out);
}

// Round 3
// 626.968 us; speedup vs baseline: 1.0050x; 1.0050x over previous
//
#include <hip/hip_runtime.h>
#include <hip/hip_bf16.h>
#include <cstdint>
#include <cstddef>

#define DM   1024
#define VG   2048
#define QKD  128
#define NB   8
#define SEQ  2048
#define NH   4224      // 2*VG + QKD
#define NHP  4352      // NH padded to multiple of 256
#define MTOT 16384     // NB*SEQ
#define CH   1024      // attention query-row chunk per batch (P overlays xb)

typedef __bf16 bf16;
typedef __attribute__((ext_vector_type(8))) __bf16 bf16x8;
typedef __attribute__((ext_vector_type(4))) float f32x4;

__device__ __forceinline__ void gload16(void* lds, const void* g) {
  __builtin_amdgcn_global_load_lds(
      (const __attribute__((address_space(1))) uint32_t*)g,
      (__attribute__((address_space(3))) uint32_t*)lds, 16, 0, 0);
}

// ---------------------------------------------------------------------------
// 256x256 GEMM core, BK=32, 4-slot LDS ring, 8 waves (2M x 4N), 512 threads.
// C = A(256 x K) * Bt(256 x K)^T, row stride K for both.
// Schedule per K-step t:
//   stage(t+3) -> s_waitcnt vmcnt(12) -> s_barrier   (tile t globally landed)
//   ds_read frags (swizzled) -> MFMA x32 (setprio 1) -> s_barrier
// LDS swizzle: 16B slot s_phys = s_log ^ ((row>>1)&3), applied to global
// source on stage and to ds_read address (involution, both sides - rule #21).
// ---------------------------------------------------------------------------

__device__ __forceinline__ void stage_tile(bf16* ldsA, bf16* ldsB,
                                           const bf16* __restrict__ Ab,
                                           const bf16* __restrict__ Bb,
                                           int K, int k0) {
  const int t = threadIdx.x;
#pragma unroll
  for (int i = 0; i < 2; ++i) {
    const int q  = i * 512 + t;             // 16B chunk index 0..1023
    const int r  = q >> 2;                  // row 0..255 (4 chunks/row)
    const int sl = (q & 3) ^ ((r >> 1) & 3);// logical 16B slot for this dest
    gload16(ldsA + (size_t)q * 8, Ab + (size_t)r * K + k0 + sl * 8);
    gload16(ldsB + (size_t)q * 8, Bb + (size_t)r * K + k0 + sl * 8);
  }
}

__device__ __forceinline__ void gemm256_core(const bf16* __restrict__ Ab,
                                             const bf16* __restrict__ Bb,
                                             int K, f32x4 acc[8][4]) {
  __shared__ alignas(16) bf16 ring[4][2][256 * 32];  // 128 KiB
  const int lane = threadIdx.x & 63;
  const int wid  = threadIdx.x >> 6;   // 0..7
  const int wr   = wid >> 2;           // 0..1  (M half)
  const int wc   = wid & 3;            // 0..3  (N quarter)
  const int lr   = lane & 15;
  const int kg   = lane >> 4;          // 16B slot 0..3

#pragma unroll
  for (int m = 0; m < 8; ++m)
#pragma unroll
    for (int n = 0; n < 4; ++n)
      acc[m][n] = f32x4{0.f, 0.f, 0.f, 0.f};

  const int NT = K >> 5;
  stage_tile(ring[0][0], ring[0][1], Ab, Bb, K, 0);
  stage_tile(ring[1][0], ring[1][1], Ab, Bb, K, 32);
  stage_tile(ring[2][0], ring[2][1], Ab, Bb, K, 64);

  for (int tt = 0; tt < NT; ++tt) {
    const int s = tt & 3;
    if (tt + 3 < NT) {
      const int ns = (tt + 3) & 3;
      stage_tile(ring[ns][0], ring[ns][1], Ab, Bb, K, (tt + 3) << 5);
      asm volatile("s_waitcnt vmcnt(12)" ::: "memory");
    } else if (tt + 2 < NT) {
      asm volatile("s_waitcnt vmcnt(8)" ::: "memory");
    } else if (tt + 1 < NT) {
      asm volatile("s_waitcnt vmcnt(4)" ::: "memory");
    } else {
      asm volatile("s_waitcnt vmcnt(0)" ::: "memory");
    }
    __builtin_amdgcn_s_barrier();      // globalizes the vmcnt wait
    asm volatile("" ::: "memory");

    const bf16* pa = ring[s][0];
    const bf16* pb = ring[s][1];
    bf16x8 af[8], bfr[4];
#pragma unroll
    for (int m = 0; m < 8; ++m) {
      const int r = wr * 128 + m * 16 + lr;
      af[m] = *(const bf16x8*)&pa[r * 32 + ((kg ^ ((r >> 1) & 3)) << 3)];
    }
#pragma unroll
    for (int n = 0; n < 4; ++n) {
      const int r = wc * 64 + n * 16 + lr;
      bfr[n] = *(const bf16x8*)&pb[r * 32 + ((kg ^ ((r >> 1) & 3)) << 3)];
    }
    __builtin_amdgcn_s_setprio(1);
#pragma unroll
    for (int m = 0; m < 8; ++m)
#pragma unroll
      for (int n = 0; n < 4; ++n)
        acc[m][n] = __builtin_amdgcn_mfma_f32_16x16x32_bf16(af[m], bfr[n], acc[m][n], 0, 0, 0);
    __builtin_amdgcn_s_setprio(0);
    asm volatile("" ::: "memory");
    __builtin_amdgcn_s_barrier();      // seals reads of slot s before reuse
  }
}

// C/D mapping within the wave's 128x64 subtile:
//   row = wr*128 + m*16 + (lane>>4)*4 + j ; col = wc*64 + n*16 + (lane&15)

// ---------------- conversion / transpose ----------------

__global__ __launch_bounds__(256)
void k_cvt(const float* __restrict__ in, bf16* __restrict__ out, int n8) {
  const int i = blockIdx.x * 256 + threadIdx.x;
  if (i >= n8) return;
  const float* p = in + (size_t)i * 8;
  bf16x8 o;
#pragma unroll
  for (int j = 0; j < 8; ++j) o[j] = (bf16)p[j];
  *(bf16x8*)(out + (size_t)i * 8) = o;
}

// in: R x C fp32 (row-major) -> out: C x R bf16
__global__ __launch_bounds__(256)
void k_transpose(const float* __restrict__ in, bf16* __restrict__ out, int R, int C) {
  __shared__ float tile[64][65];
  const int r0 = blockIdx.y * 64, c0 = blockIdx.x * 64;
  const int t = threadIdx.x;
#pragma unroll
  for (int i = 0; i < 16; ++i) {
    const int flat = i * 256 + t;
    const int r = flat >> 6, c = flat & 63;
    tile[r][c] = in[(size_t)(r0 + r) * C + (c0 + c)];
  }
  __syncthreads();
#pragma unroll
  for (int i = 0; i < 16; ++i) {
    const int flat = i * 256 + t;
    const int r = flat >> 6, c = flat & 63;
    out[(size_t)(c0 + r) * R + (r0 + c)] = (bf16)tile[c][r];
  }
}

// In-place per-batch transpose of a SEQ x SEQ bf16 matrix (tile-pair swap).
__global__ __launch_bounds__(256)
void k_vtrans(bf16* __restrict__ a) {
  const int bi = blockIdx.y, bj = blockIdx.x;
  if (bj < bi) return;
  bf16* A = a + (size_t)blockIdx.z * SEQ * SEQ;
  __shared__ float t0[64][65];
  __shared__ float t1[64][65];
  const int r0 = bi * 64, c0 = bj * 64;
  const int t = threadIdx.x;
  const bool diag = (bi == bj);
#pragma unroll
  for (int i = 0; i < 16; ++i) {
    const int flat = i * 256 + t;
    const int r = flat >> 6, c = flat & 63;
    t0[r][c] = (float)A[(size_t)(r0 + r) * SEQ + (c0 + c)];
    if (!diag) t1[r][c] = (float)A[(size_t)(c0 + r) * SEQ + (r0 + c)];
  }
  __syncthreads();
#pragma unroll
  for (int i = 0; i < 16; ++i) {
    const int flat = i * 256 + t;
    const int r = flat >> 6, c = flat & 63;
    A[(size_t)(r0 + r) * SEQ + (c0 + c)] = (bf16)(diag ? t0[c][r] : t1[c][r]);
    if (!diag) A[(size_t)(c0 + r) * SEQ + (r0 + c)] = (bf16)t0[c][r];
  }
}

// ---------------- GEMM1: h = x@W_i + b_i ; SiLU ; split u/v/q/k ----------------

__global__ __launch_bounds__(512, 2)
void k_gemm1(const bf16* __restrict__ xb, const bf16* __restrict__ wibt,
             const float* __restrict__ b_i,
             const float* __restrict__ q_w, const float* __restrict__ q_b,
             const float* __restrict__ k_w, const float* __restrict__ k_b,
             bf16* __restrict__ u, bf16* __restrict__ v,
             bf16* __restrict__ q, bf16* __restrict__ k) {
  int wg = blockIdx.x;                       // 1088 = 64 x 17
  wg = (wg & 7) * 136 + (wg >> 3);           // XCD swizzle (bijective)
  const int bm0 = (wg / 17) * 256;
  const int bn0 = (wg % 17) * 256;
  f32x4 acc[8][4];
  gemm256_core(xb + (size_t)bm0 * DM, wibt + (size_t)bn0 * DM, DM, acc);
  const int lane = threadIdx.x & 63;
  const int wid  = threadIdx.x >> 6;
  const int wr = wid >> 2, wc = wid & 3;
  const float rs = 0.08838834764831845f;     // 1/sqrt(128)
#pragma unroll
  for (int m = 0; m < 8; ++m)
#pragma unroll
    for (int n = 0; n < 4; ++n)
#pragma unroll
      for (int j = 0; j < 4; ++j) {
        const int row = bm0 + wr * 128 + m * 16 + ((lane >> 4) << 2) + j;
        const int col = bn0 + wc * 64 + n * 16 + (lane & 15);
        if (col >= NH) continue;
        const float h = acc[m][n][j] + b_i[col];
        const float s = h / (1.f + __expf(-h));  // silu
        if (col < VG) {
          u[(size_t)row * VG + col] = (bf16)s;
        } else if (col < 2 * VG) {
          v[(size_t)row * VG + (col - VG)] = (bf16)s;
        } else {
          const int c = col - 2 * VG;
          q[(size_t)row * QKD + c] = (bf16)((s * q_w[c] + q_b[c]) * rs);
          k[(size_t)row * QKD + c] = (bf16)(s * k_w[c] + k_b[c]);
        }
      }
}

// ---------------- S-chunk = q[m0:m0+CH] @ k^T (per batch) ----------------

__global__ __launch_bounds__(512, 2)
void k_gemmS(const bf16* __restrict__ q, const bf16* __restrict__ k,
             bf16* __restrict__ P, int m0) {
  int wg = blockIdx.x;                       // 256 = 8b x 4m x 8n
  wg = (wg & 7) * 32 + (wg >> 3);
  const int b   = wg >> 5;
  const int bm0 = ((wg >> 3) & 3) * 256;
  const int bn0 = (wg & 7) * 256;
  f32x4 acc[8][4];
  gemm256_core(q + ((size_t)b * SEQ + m0 + bm0) * QKD,
               k + ((size_t)b * SEQ + bn0) * QKD, QKD, acc);
  bf16* Pb = P + (size_t)b * CH * SEQ;
  const int lane = threadIdx.x & 63;
  const int wid  = threadIdx.x >> 6;
  const int wr = wid >> 2, wc = wid & 3;
#pragma unroll
  for (int m = 0; m < 8; ++m)
#pragma unroll
    for (int n = 0; n < 4; ++n)
#pragma unroll
      for (int j = 0; j < 4; ++j) {
        const int row = bm0 + wr * 128 + m * 16 + ((lane >> 4) << 2) + j;
        const int col = bn0 + wc * 64 + n * 16 + (lane & 15);
        Pb[(size_t)row * SEQ + col] = (bf16)acc[m][n][j];
      }
}

// ---------------- row softmax over chunk (in place), key padding mask ----------------

__global__ __launch_bounds__(256)
void k_softmax(bf16* __restrict__ P, const int* __restrict__ mask) {
  const int row = blockIdx.x;       // 0..NB*CH-1
  const int b = row >> 10;          // row / CH
  const int t = threadIdx.x;
  bf16* srow = P + (size_t)row * SEQ;
  const int* mrow = mask + (size_t)b * SEQ;
  bf16x8 vv = *(const bf16x8*)(srow + t * 8);
  float f[8];
  float mx = -1e30f;
#pragma unroll
  for (int j = 0; j < 8; ++j) {
    const bool ok = mrow[t * 8 + j] != 0;
    f[j] = ok ? (float)vv[j] : -1e30f;
    mx = fmaxf(mx, f[j]);
  }
#pragma unroll
  for (int off = 32; off > 0; off >>= 1) mx = fmaxf(mx, __shfl_xor(mx, off));
  __shared__ float redm[4], reds[4];
  if ((t & 63) == 0) redm[t >> 6] = mx;
  __syncthreads();
  mx = fmaxf(fmaxf(redm[0], redm[1]), fmaxf(redm[2], redm[3]));
  float sum = 0.f;
#pragma unroll
  for (int j = 0; j < 8; ++j) {
    f[j] = (f[j] > -1e29f) ? __expf(f[j] - mx) : 0.f;
    sum += f[j];
  }
#pragma unroll
  for (int off = 32; off > 0; off >>= 1) sum += __shfl_xor(sum, off);
  if ((t & 63) == 0) reds[t >> 6] = sum;
  __syncthreads();
  sum = reds[0] + reds[1] + reds[2] + reds[3];
  const float inv = 1.f / sum;
#pragma unroll
  for (int j = 0; j < 8; ++j) vv[j] = (bf16)(f[j] * inv);
  *(bf16x8*)(srow + t * 8) = vv;
}

// ---------------- o = u .* (P @ v), written over u in place ----------------

__global__ __launch_bounds__(512, 2)
void k_gemmO(const bf16* __restrict__ P, const bf16* __restrict__ vT,
             bf16* uo, int m0) {
  int wg = blockIdx.x;                       // 256 = 8b x 4m x 8n
  wg = (wg & 7) * 32 + (wg >> 3);
  const int b   = wg >> 5;
  const int bm0 = ((wg >> 3) & 3) * 256;
  const int bn0 = (wg & 7) * 256;
  f32x4 acc[8][4];
  gemm256_core(P + ((size_t)b * CH + bm0) * SEQ,
               vT + ((size_t)b * VG + bn0) * SEQ, SEQ, acc);
  const int lane = threadIdx.x & 63;
  const int wid  = threadIdx.x >> 6;
  const int wr = wid >> 2, wc = wid & 3;
#pragma unroll
  for (int m = 0; m < 8; ++m)
#pragma unroll
    for (int n = 0; n < 4; ++n)
#pragma unroll
      for (int j = 0; j < 4; ++j) {
        const int row = bm0 + wr * 128 + m * 16 + ((lane >> 4) << 2) + j;
        const int col = bn0 + wc * 64 + n * 16 + (lane & 15);
        const size_t idx = ((size_t)(b * SEQ + m0 + row)) * VG + col;
        uo[idx] = (bf16)(acc[m][n][j] * (float)uo[idx]);
      }
}

// ---------------- out = o @ W_o + b_o (fp32 out) ----------------

__global__ __launch_bounds__(512, 2)
void k_gemm2(const bf16* __restrict__ o, const bf16* __restrict__ wobt,
             const float* __restrict__ b_o, float* __restrict__ out) {
  int wg = blockIdx.x;                       // 256 = 64m x 4n
  wg = (wg & 7) * 32 + (wg >> 3);
  const int bm0 = (wg >> 2) * 256;
  const int bn0 = (wg & 3) * 256;
  f32x4 acc[8][4];
  gemm256_core(o + (size_t)bm0 * VG, wobt + (size_t)bn0 * VG, VG, acc);
  const int lane = threadIdx.x & 63;
  const int wid  = threadIdx.x >> 6;
  const int wr = wid >> 2, wc = wid & 3;
#pragma unroll
  for (int m = 0; m < 8; ++m)
#pragma unroll
    for (int n = 0; n < 4; ++n)
#pragma unroll
      for (int j = 0; j < 4; ++j) {
        const int row = bm0 + wr * 128 + m * 16 + ((lane >> 4) << 2) + j;
        const int col = bn0 + wc * 64 + n * 16 + (lane & 15);
        out[(size_t)row * DM + col] = acc[m][n][j] + b_o[col];
      }
}

// ---------------- launch ----------------
// Workspace (189.4 MB): wobt 4.2 | xb/P 33.6 | wibt(pad) 8.9 | qb 4.2
//                       | kb 4.2 | uo 67.1 | v 67.1

extern "C" void kernel_launch(void* const* d_in, const int* in_sizes, int n_in,
                              void* d_out, int out_size, void* d_ws, size_t ws_size,
                              hipStream_t stream) {
  const float* x   = (const float*)d_in[0];
  const int*   pm  = (const int*)d_in[1];
  const float* W_i = (const float*)d_in[2];
  const float* b_i = (const float*)d_in[3];
  const float* q_w = (const float*)d_in[4];
  const float* q_b = (const float*)d_in[5];
  const float* k_w = (const float*)d_in[6];
  const float* k_b = (const float*)d_in[7];
  const float* W_o = (const float*)d_in[8];
  const float* b_o = (const float*)d_in[9];
  float* out = (float*)d_out;

  char* w = (char*)d_ws;
  bf16* wobt = (bf16*)w; w += (size_t)DM * VG * 2;
  bf16* xb   = (bf16*)w; w += (size_t)MTOT * DM * 2;   // reused as P chunk
  bf16* wibt = (bf16*)w; w += (size_t)NHP * DM * 2;    // padded to 4352 rows
  bf16* qb   = (bf16*)w; w += (size_t)MTOT * QKD * 2;
  bf16* kb   = (bf16*)w; w += (size_t)MTOT * QKD * 2;
  bf16* uo   = (bf16*)w; w += (size_t)MTOT * VG * 2;   // u, then o (in place)
  bf16* vb   = (bf16*)w; w += (size_t)MTOT * VG * 2;   // v, then vT (in place)
  bf16* Pc   = xb;

  // x -> bf16
  k_cvt<<<dim3(MTOT * DM / 8 / 256), 256, 0, stream>>>(x, xb, MTOT * DM / 8);
  // W_i (DM x NH) -> (NH x DM) bf16, pad rows [NH, NHP) zeroed
  hipMemsetAsync(wibt + (size_t)NH * DM, 0, (size_t)(NHP - NH) * DM * 2, stream);
  k_transpose<<<dim3(NH / 64, DM / 64), 256, 0, stream>>>(W_i, wibt, DM, NH);
  // W_o (VG x DM) -> (DM x VG) bf16
  k_transpose<<<dim3(DM / 64, VG / 64), 256, 0, stream>>>(W_o, wobt, VG, DM);
  // GEMM1 + silu + split (xb dead afterwards)
  k_gemm1<<<dim3(64 * 17), 512, 0, stream>>>(
      xb, wibt, b_i, q_w, q_b, k_w, k_b, uo, vb, qb, kb);
  // v -> v^T in place (square per batch)
  k_vtrans<<<dim3(SEQ / 64, SEQ / 64, NB), 256, 0, stream>>>(vb);
  // attention in CH-row chunks; P overlays xb
  for (int c = 0; c < SEQ / CH; ++c) {
    const int m0 = c * CH;
    k_gemmS<<<dim3(NB * 4 * 8), 512, 0, stream>>>(qb, kb, Pc, m0);
    k_softmax<<<dim3(NB * CH), 256, 0, stream>>>(Pc, pm);
    k_gemmO<<<dim3(NB * 4 * 8), 512, 0, stream>>>(Pc, vb, uo, m0);
  }
  // out = o @ W_o + b_o
  k_gemm2<<<dim3(64 * 4), 512, 0, stream>>>(uo, wobt, b_o, out);
}

// Round 4
// 596.733 us; speedup vs baseline: 1.0559x; 1.0507x over previous
//
#include <hip/hip_runtime.h>
#include <hip/hip_bf16.h>
#include <cstdint>
#include <cstddef>

#define DM   1024
#define VG   2048
#define QKD  128
#define NB   8
#define SEQ  2048
#define NH   4224      // 2*VG + QKD
#define NHP  4352      // NH padded to multiple of 256
#define MTOT 16384     // NB*SEQ
#define CH   1024      // attention query-row chunk per batch (P overlays xb)

typedef __bf16 bf16;
typedef __attribute__((ext_vector_type(8))) __bf16 bf16x8;
typedef __attribute__((ext_vector_type(4))) float f32x4;

__device__ __forceinline__ void gload16(void* lds, const void* g) {
  __builtin_amdgcn_global_load_lds(
      (const __attribute__((address_space(1))) uint32_t*)g,
      (__attribute__((address_space(3))) uint32_t*)lds, 16, 0, 0);
}

// ---------------------------------------------------------------------------
// 256x256 GEMM core, BK=64, 8 waves (2M x 4N), 512 threads, pipelined.
// LDS: 2 buffers x 4 units (A-klo, A-khi, B-klo, B-khi), each 256 rows x 32
// bf16 (16 KiB). Unit stage = 2 global_load_lds_dwordx4 per thread, linear
// dest; source pre-swizzled: slot_log = slot_phys ^ ((row>>1)&3). Reads use
// the same XOR -> 2-way bank access (free).
// Per K-tile t (buf b=t&1): stage lo(t+1) -> vmcnt(8) -> barrier ->
//   {12 ds_read, 16 MFMA}{4 ds_read, 16 MFMA} -> stage hi(t+1) -> vmcnt(8)
//   -> barrier -> {8 ds_read, 16 MFMA}{4 ds_read, 16 MFMA}.
// vmcnt oldest-first accounting: at each wait exactly the 4 loads of the
// k-half about to be consumed are the oldest outstanding; 8 newer may fly.
// Tail iter (no stage): vmcnt(4) then vmcnt(0).
// ---------------------------------------------------------------------------

__device__ __forceinline__ void stage_unit(bf16* unit, const bf16* __restrict__ src,
                                           int K, int kbase) {
  const int t = threadIdx.x;
#pragma unroll
  for (int i = 0; i < 2; ++i) {
    const int c = i * 512 + t;            // chunk 0..1023
    const int r = c >> 2;                 // row 0..255
    const int l = (c & 3) ^ ((r >> 1) & 3);  // logical 16B slot
    gload16(unit + (size_t)c * 8, src + (size_t)r * K + kbase + l * 8);
  }
}

__device__ __forceinline__ void gemm256_core(const bf16* __restrict__ Ab,
                                             const bf16* __restrict__ Bb,
                                             int K, f32x4 acc[8][4]) {
  __shared__ alignas(16) bf16 lds[2][4][256 * 32];  // 128 KiB
  const int lane = threadIdx.x & 63;
  const int wid  = threadIdx.x >> 6;
  const int wr   = wid >> 2;            // 0..1
  const int wc   = wid & 3;             // 0..3
  const int lr   = lane & 15;
  const int kg   = lane >> 4;           // 16B slot 0..3

#pragma unroll
  for (int m = 0; m < 8; ++m)
#pragma unroll
    for (int n = 0; n < 4; ++n)
      acc[m][n] = f32x4{0.f, 0.f, 0.f, 0.f};

  const int NT = K >> 6;
  // prologue: buf0, order lo(A,B) then hi(A,B)
  stage_unit(lds[0][0], Ab, K, 0);
  stage_unit(lds[0][2], Bb, K, 0);
  stage_unit(lds[0][1], Ab, K, 32);
  stage_unit(lds[0][3], Bb, K, 32);

  for (int tt = 0; tt < NT; ++tt) {
    const int b = tt & 1;
    const int k0 = (tt + 1) << 6;
    const bool st = (tt + 1 < NT);

    // ---- k-half 0 ----
    if (st) {
      stage_unit(lds[b ^ 1][0], Ab, K, k0);
      stage_unit(lds[b ^ 1][2], Bb, K, k0);
      asm volatile("s_waitcnt vmcnt(8)" ::: "memory");
    } else {
      asm volatile("s_waitcnt vmcnt(4)" ::: "memory");
    }
    __builtin_amdgcn_s_barrier();
    asm volatile("" ::: "memory");
    {
      const bf16* ua = lds[b][0];
      const bf16* ub = lds[b][2];
      bf16x8 bfr[4], af[4];
#pragma unroll
      for (int n = 0; n < 4; ++n) {
        const int r = wc * 64 + n * 16 + lr;
        bfr[n] = *(const bf16x8*)&ub[r * 32 + ((kg ^ ((r >> 1) & 3)) << 3)];
      }
#pragma unroll
      for (int m = 0; m < 4; ++m) {
        const int r = wr * 128 + m * 16 + lr;
        af[m] = *(const bf16x8*)&ua[r * 32 + ((kg ^ ((r >> 1) & 3)) << 3)];
      }
      __builtin_amdgcn_s_setprio(1);
#pragma unroll
      for (int m = 0; m < 4; ++m)
#pragma unroll
        for (int n = 0; n < 4; ++n)
          acc[m][n] = __builtin_amdgcn_mfma_f32_16x16x32_bf16(af[m], bfr[n], acc[m][n], 0, 0, 0);
      __builtin_amdgcn_s_setprio(0);
#pragma unroll
      for (int m = 0; m < 4; ++m) {
        const int r = wr * 128 + (m + 4) * 16 + lr;
        af[m] = *(const bf16x8*)&ua[r * 32 + ((kg ^ ((r >> 1) & 3)) << 3)];
      }
      __builtin_amdgcn_s_setprio(1);
#pragma unroll
      for (int m = 0; m < 4; ++m)
#pragma unroll
        for (int n = 0; n < 4; ++n)
          acc[m + 4][n] = __builtin_amdgcn_mfma_f32_16x16x32_bf16(af[m], bfr[n], acc[m + 4][n], 0, 0, 0);
      __builtin_amdgcn_s_setprio(0);
    }
    asm volatile("" ::: "memory");

    // ---- k-half 1 ----
    if (st) {
      stage_unit(lds[b ^ 1][1], Ab, K, k0 + 32);
      stage_unit(lds[b ^ 1][3], Bb, K, k0 + 32);
      asm volatile("s_waitcnt vmcnt(8)" ::: "memory");
    } else {
      asm volatile("s_waitcnt vmcnt(0)" ::: "memory");
    }
    __builtin_amdgcn_s_barrier();
    asm volatile("" ::: "memory");
    {
      const bf16* ua = lds[b][1];
      const bf16* ub = lds[b][3];
      bf16x8 bfr[4], af[4];
#pragma unroll
      for (int n = 0; n < 4; ++n) {
        const int r = wc * 64 + n * 16 + lr;
        bfr[n] = *(const bf16x8*)&ub[r * 32 + ((kg ^ ((r >> 1) & 3)) << 3)];
      }
#pragma unroll
      for (int m = 0; m < 4; ++m) {
        const int r = wr * 128 + m * 16 + lr;
        af[m] = *(const bf16x8*)&ua[r * 32 + ((kg ^ ((r >> 1) & 3)) << 3)];
      }
      __builtin_amdgcn_s_setprio(1);
#pragma unroll
      for (int m = 0; m < 4; ++m)
#pragma unroll
        for (int n = 0; n < 4; ++n)
          acc[m][n] = __builtin_amdgcn_mfma_f32_16x16x32_bf16(af[m], bfr[n], acc[m][n], 0, 0, 0);
      __builtin_amdgcn_s_setprio(0);
#pragma unroll
      for (int m = 0; m < 4; ++m) {
        const int r = wr * 128 + (m + 4) * 16 + lr;
        af[m] = *(const bf16x8*)&ua[r * 32 + ((kg ^ ((r >> 1) & 3)) << 3)];
      }
      __builtin_amdgcn_s_setprio(1);
#pragma unroll
      for (int m = 0; m < 4; ++m)
#pragma unroll
        for (int n = 0; n < 4; ++n)
          acc[m + 4][n] = __builtin_amdgcn_mfma_f32_16x16x32_bf16(af[m], bfr[n], acc[m + 4][n], 0, 0, 0);
      __builtin_amdgcn_s_setprio(0);
    }
    asm volatile("" ::: "memory");
  }
}

// C/D mapping within the wave's 128x64 subtile:
//   row = wr*128 + m*16 + (lane>>4)*4 + j ; col = wc*64 + n*16 + (lane&15)

// ---------------- conversion / transpose ----------------

__global__ __launch_bounds__(256)
void k_cvt(const float* __restrict__ in, bf16* __restrict__ out, int n8) {
  const int i = blockIdx.x * 256 + threadIdx.x;
  if (i >= n8) return;
  const float* p = in + (size_t)i * 8;
  bf16x8 o;
#pragma unroll
  for (int j = 0; j < 8; ++j) o[j] = (bf16)p[j];
  *(bf16x8*)(out + (size_t)i * 8) = o;
}

// in: R x C fp32 (row-major) -> out: C x R bf16
__global__ __launch_bounds__(256)
void k_transpose(const float* __restrict__ in, bf16* __restrict__ out, int R, int C) {
  __shared__ float tile[64][65];
  const int r0 = blockIdx.y * 64, c0 = blockIdx.x * 64;
  const int t = threadIdx.x;
#pragma unroll
  for (int i = 0; i < 16; ++i) {
    const int flat = i * 256 + t;
    const int r = flat >> 6, c = flat & 63;
    tile[r][c] = in[(size_t)(r0 + r) * C + (c0 + c)];
  }
  __syncthreads();
#pragma unroll
  for (int i = 0; i < 16; ++i) {
    const int flat = i * 256 + t;
    const int r = flat >> 6, c = flat & 63;
    out[(size_t)(c0 + r) * R + (r0 + c)] = (bf16)tile[c][r];
  }
}

// In-place per-batch transpose of a SEQ x SEQ bf16 matrix (tile-pair swap).
__global__ __launch_bounds__(256)
void k_vtrans(bf16* __restrict__ a) {
  const int bi = blockIdx.y, bj = blockIdx.x;
  if (bj < bi) return;
  bf16* A = a + (size_t)blockIdx.z * SEQ * SEQ;
  __shared__ float t0[64][65];
  __shared__ float t1[64][65];
  const int r0 = bi * 64, c0 = bj * 64;
  const int t = threadIdx.x;
  const bool diag = (bi == bj);
#pragma unroll
  for (int i = 0; i < 16; ++i) {
    const int flat = i * 256 + t;
    const int r = flat >> 6, c = flat & 63;
    t0[r][c] = (float)A[(size_t)(r0 + r) * SEQ + (c0 + c)];
    if (!diag) t1[r][c] = (float)A[(size_t)(c0 + r) * SEQ + (r0 + c)];
  }
  __syncthreads();
#pragma unroll
  for (int i = 0; i < 16; ++i) {
    const int flat = i * 256 + t;
    const int r = flat >> 6, c = flat & 63;
    A[(size_t)(r0 + r) * SEQ + (c0 + c)] = (bf16)(diag ? t0[c][r] : t1[c][r]);
    if (!diag) A[(size_t)(c0 + r) * SEQ + (r0 + c)] = (bf16)t0[c][r];
  }
}

// ---------------- GEMM1: h = x@W_i + b_i ; SiLU ; split u/v/q/k ----------------

__global__ __launch_bounds__(512, 2)
void k_gemm1(const bf16* __restrict__ xb, const bf16* __restrict__ wibt,
             const float* __restrict__ b_i,
             const float* __restrict__ q_w, const float* __restrict__ q_b,
             const float* __restrict__ k_w, const float* __restrict__ k_b,
             bf16* __restrict__ u, bf16* __restrict__ v,
             bf16* __restrict__ q, bf16* __restrict__ k) {
  int wg = blockIdx.x;                       // 1088 = 64 x 17
  wg = (wg & 7) * 136 + (wg >> 3);           // XCD swizzle (bijective)
  const int bm0 = (wg / 17) * 256;
  const int bn0 = (wg % 17) * 256;
  f32x4 acc[8][4];
  gemm256_core(xb + (size_t)bm0 * DM, wibt + (size_t)bn0 * DM, DM, acc);
  const int lane = threadIdx.x & 63;
  const int wid  = threadIdx.x >> 6;
  const int wr = wid >> 2, wc = wid & 3;
  const float rs = 0.08838834764831845f;     // 1/sqrt(128)
#pragma unroll
  for (int m = 0; m < 8; ++m)
#pragma unroll
    for (int n = 0; n < 4; ++n)
#pragma unroll
      for (int j = 0; j < 4; ++j) {
        const int row = bm0 + wr * 128 + m * 16 + ((lane >> 4) << 2) + j;
        const int col = bn0 + wc * 64 + n * 16 + (lane & 15);
        if (col >= NH) continue;
        const float h = acc[m][n][j] + b_i[col];
        const float s = h / (1.f + __expf(-h));  // silu
        if (col < VG) {
          u[(size_t)row * VG + col] = (bf16)s;
        } else if (col < 2 * VG) {
          v[(size_t)row * VG + (col - VG)] = (bf16)s;
        } else {
          const int c = col - 2 * VG;
          q[(size_t)row * QKD + c] = (bf16)((s * q_w[c] + q_b[c]) * rs);
          k[(size_t)row * QKD + c] = (bf16)(s * k_w[c] + k_b[c]);
        }
      }
}

// ---------------- S-chunk = q[m0:m0+CH] @ k^T (per batch) ----------------

__global__ __launch_bounds__(512, 2)
void k_gemmS(const bf16* __restrict__ q, const bf16* __restrict__ k,
             bf16* __restrict__ P, int m0) {
  int wg = blockIdx.x;                       // 256 = 8b x 4m x 8n
  wg = (wg & 7) * 32 + (wg >> 3);
  const int b   = wg >> 5;
  const int bm0 = ((wg >> 3) & 3) * 256;
  const int bn0 = (wg & 7) * 256;
  f32x4 acc[8][4];
  gemm256_core(q + ((size_t)b * SEQ + m0 + bm0) * QKD,
               k + ((size_t)b * SEQ + bn0) * QKD, QKD, acc);
  bf16* Pb = P + (size_t)b * CH * SEQ;
  const int lane = threadIdx.x & 63;
  const int wid  = threadIdx.x >> 6;
  const int wr = wid >> 2, wc = wid & 3;
#pragma unroll
  for (int m = 0; m < 8; ++m)
#pragma unroll
    for (int n = 0; n < 4; ++n)
#pragma unroll
      for (int j = 0; j < 4; ++j) {
        const int row = bm0 + wr * 128 + m * 16 + ((lane >> 4) << 2) + j;
        const int col = bn0 + wc * 64 + n * 16 + (lane & 15);
        Pb[(size_t)row * SEQ + col] = (bf16)acc[m][n][j];
      }
}

// ---------------- row softmax over chunk (in place), key padding mask ----------------

__global__ __launch_bounds__(256)
void k_softmax(bf16* __restrict__ P, const int* __restrict__ mask) {
  const int row = blockIdx.x;       // 0..NB*CH-1
  const int b = row >> 10;          // row / CH
  const int t = threadIdx.x;
  bf16* srow = P + (size_t)row * SEQ;
  const int* mrow = mask + (size_t)b * SEQ;
  bf16x8 vv = *(const bf16x8*)(srow + t * 8);
  float f[8];
  float mx = -1e30f;
#pragma unroll
  for (int j = 0; j < 8; ++j) {
    const bool ok = mrow[t * 8 + j] != 0;
    f[j] = ok ? (float)vv[j] : -1e30f;
    mx = fmaxf(mx, f[j]);
  }
#pragma unroll
  for (int off = 32; off > 0; off >>= 1) mx = fmaxf(mx, __shfl_xor(mx, off));
  __shared__ float redm[4], reds[4];
  if ((t & 63) == 0) redm[t >> 6] = mx;
  __syncthreads();
  mx = fmaxf(fmaxf(redm[0], redm[1]), fmaxf(redm[2], redm[3]));
  float sum = 0.f;
#pragma unroll
  for (int j = 0; j < 8; ++j) {
    f[j] = (f[j] > -1e29f) ? __expf(f[j] - mx) : 0.f;
    sum += f[j];
  }
#pragma unroll
  for (int off = 32; off > 0; off >>= 1) sum += __shfl_xor(sum, off);
  if ((t & 63) == 0) reds[t >> 6] = sum;
  __syncthreads();
  sum = reds[0] + reds[1] + reds[2] + reds[3];
  const float inv = 1.f / sum;
#pragma unroll
  for (int j = 0; j < 8; ++j) vv[j] = (bf16)(f[j] * inv);
  *(bf16x8*)(srow + t * 8) = vv;
}

// ---------------- o = u .* (P @ v), written over u in place ----------------

__global__ __launch_bounds__(512, 2)
void k_gemmO(const bf16* __restrict__ P, const bf16* __restrict__ vT,
             bf16* uo, int m0) {
  int wg = blockIdx.x;                       // 256 = 8b x 4m x 8n
  wg = (wg & 7) * 32 + (wg >> 3);
  const int b   = wg >> 5;
  const int bm0 = ((wg >> 3) & 3) * 256;
  const int bn0 = (wg & 7) * 256;
  f32x4 acc[8][4];
  gemm256_core(P + ((size_t)b * CH + bm0) * SEQ,
               vT + ((size_t)b * VG + bn0) * SEQ, SEQ, acc);
  const int lane = threadIdx.x & 63;
  const int wid  = threadIdx.x >> 6;
  const int wr = wid >> 2, wc = wid & 3;
#pragma unroll
  for (int m = 0; m < 8; ++m)
#pragma unroll
    for (int n = 0; n < 4; ++n)
#pragma unroll
      for (int j = 0; j < 4; ++j) {
        const int row = bm0 + wr * 128 + m * 16 + ((lane >> 4) << 2) + j;
        const int col = bn0 + wc * 64 + n * 16 + (lane & 15);
        const size_t idx = ((size_t)(b * SEQ + m0 + row)) * VG + col;
        uo[idx] = (bf16)(acc[m][n][j] * (float)uo[idx]);
      }
}

// ---------------- out = o @ W_o + b_o (fp32 out) ----------------

__global__ __launch_bounds__(512, 2)
void k_gemm2(const bf16* __restrict__ o, const bf16* __restrict__ wobt,
             const float* __restrict__ b_o, float* __restrict__ out) {
  int wg = blockIdx.x;                       // 256 = 64m x 4n
  wg = (wg & 7) * 32 + (wg >> 3);
  const int bm0 = (wg >> 2) * 256;
  const int bn0 = (wg & 3) * 256;
  f32x4 acc[8][4];
  gemm256_core(o + (size_t)bm0 * VG, wobt + (size_t)bn0 * VG, VG, acc);
  const int lane = threadIdx.x & 63;
  const int wid  = threadIdx.x >> 6;
  const int wr = wid >> 2, wc = wid & 3;
#pragma unroll
  for (int m = 0; m < 8; ++m)
#pragma unroll
    for (int n = 0; n < 4; ++n)
#pragma unroll
      for (int j = 0; j < 4; ++j) {
        const int row = bm0 + wr * 128 + m * 16 + ((lane >> 4) << 2) + j;
        const int col = bn0 + wc * 64 + n * 16 + (lane & 15);
        out[(size_t)row * DM + col] = acc[m][n][j] + b_o[col];
      }
}

// ---------------- launch ----------------
// Workspace (189.4 MB): wobt 4.2 | xb/P 33.6 | wibt(pad) 8.9 | qb 4.2
//                       | kb 4.2 | uo 67.1 | v 67.1

extern "C" void kernel_launch(void* const* d_in, const int* in_sizes, int n_in,
                              void* d_out, int out_size, void* d_ws, size_t ws_size,
                              hipStream_t stream) {
  const float* x   = (const float*)d_in[0];
  const int*   pm  = (const int*)d_in[1];
  const float* W_i = (const float*)d_in[2];
  const float* b_i = (const float*)d_in[3];
  const float* q_w = (const float*)d_in[4];
  const float* q_b = (const float*)d_in[5];
  const float* k_w = (const float*)d_in[6];
  const float* k_b = (const float*)d_in[7];
  const float* W_o = (const float*)d_in[8];
  const float* b_o = (const float*)d_in[9];
  float* out = (float*)d_out;

  char* w = (char*)d_ws;
  bf16* wobt = (bf16*)w; w += (size_t)DM * VG * 2;
  bf16* xb   = (bf16*)w; w += (size_t)MTOT * DM * 2;   // reused as P chunk
  bf16* wibt = (bf16*)w; w += (size_t)NHP * DM * 2;    // padded to 4352 rows
  bf16* qb   = (bf16*)w; w += (size_t)MTOT * QKD * 2;
  bf16* kb   = (bf16*)w; w += (size_t)MTOT * QKD * 2;
  bf16* uo   = (bf16*)w; w += (size_t)MTOT * VG * 2;   // u, then o (in place)
  bf16* vb   = (bf16*)w; w += (size_t)MTOT * VG * 2;   // v, then vT (in place)
  bf16* Pc   = xb;

  // x -> bf16
  k_cvt<<<dim3(MTOT * DM / 8 / 256), 256, 0, stream>>>(x, xb, MTOT * DM / 8);
  // W_i (DM x NH) -> (NH x DM) bf16, pad rows [NH, NHP) zeroed
  hipMemsetAsync(wibt + (size_t)NH * DM, 0, (size_t)(NHP - NH) * DM * 2, stream);
  k_transpose<<<dim3(NH / 64, DM / 64), 256, 0, stream>>>(W_i, wibt, DM, NH);
  // W_o (VG x DM) -> (DM x VG) bf16
  k_transpose<<<dim3(DM / 64, VG / 64), 256, 0, stream>>>(W_o, wobt, VG, DM);
  // GEMM1 + silu + split (xb dead afterwards)
  k_gemm1<<<dim3(64 * 17), 512, 0, stream>>>(
      xb, wibt, b_i, q_w, q_b, k_w, k_b, uo, vb, qb, kb);
  // v -> v^T in place (square per batch)
  k_vtrans<<<dim3(SEQ / 64, SEQ / 64, NB), 256, 0, stream>>>(vb);
  // attention in CH-row chunks; P overlays xb
  for (int c = 0; c < SEQ / CH; ++c) {
    const int m0 = c * CH;
    k_gemmS<<<dim3(NB * 4 * 8), 512, 0, stream>>>(qb, kb, Pc, m0);
    k_softmax<<<dim3(NB * CH), 256, 0, stream>>>(Pc, pm);
    k_gemmO<<<dim3(NB * 4 * 8), 512, 0, stream>>>(Pc, vb, uo, m0);
  }
  // out = o @ W_o + b_o
  k_gemm2<<<dim3(64 * 4), 512, 0, stream>>>(uo, wobt, b_o, out);
}

// Round 5
// 579.692 us; speedup vs baseline: 1.0870x; 1.0294x over previous
//
#include <hip/hip_runtime.h>
#include <hip/hip_bf16.h>
#include <cstdint>
#include <cstddef>

#define DM   1024
#define VG   2048
#define QKD  128
#define NB   8
#define SEQ  2048
#define NH   4224      // 2*VG + QKD
#define NHP  4352      // NH padded to multiple of 256
#define MTOT 16384     // NB*SEQ
#define CH   1024      // attention query-row chunk per batch (P overlays xb)

typedef __bf16 bf16;
typedef __attribute__((ext_vector_type(8))) __bf16 bf16x8;
typedef __attribute__((ext_vector_type(4))) float f32x4;

__device__ __forceinline__ void gload16(void* lds, const void* g) {
  __builtin_amdgcn_global_load_lds(
      (const __attribute__((address_space(1))) uint32_t*)g,
      (__attribute__((address_space(3))) uint32_t*)lds, 16, 0, 0);
}

#define FENCE() asm volatile("" ::: "memory")
#define BAR()  do { FENCE(); __builtin_amdgcn_s_barrier(); FENCE(); } while (0)

// ---------------------------------------------------------------------------
// 256x256 GEMM core v3 — m201-style 4-phase quadrant pipeline.
// BK=64, 2 LDS buffers (A 256x64 + B 256x64 each, 128 KiB total), 8 waves.
// LDS swizzle: 16B slot s_phys = s_log ^ (row & 7) (8 slots/row) — both sides.
// Per K-tile t (buf=t&1), phases = C-quadrants (mh,nh):
//  p0: stage B(t+1); vmcnt(4); pre-read 8 B-frags (sealed @ t-1.p3 barrier);
//      BAR (globalizes A(t) seal); read A-mh0; 16 MFMA (mh0,nh0)
//  p1: stage A(t+1); BAR; 16 MFMA (mh0,nh1)
//  p2: pre-read A-mh1 (sealed @ p0 barrier); BAR; 16 MFMA (mh1,nh0)
//  p3: vmcnt(4) (retires B(t+1), 3-phase flight); BAR (globalizes B(t+1));
//      16 MFMA (mh1,nh1)
// vmcnt never 0 in steady state; every staged matrix has 3 phases of flight.
// WAR: any overwrite is >=2 barriers after the last read of that region.
// ---------------------------------------------------------------------------

__device__ __forceinline__ void stage_mat(bf16* dst, const bf16* __restrict__ src,
                                          int K, int k0) {
  const int t = threadIdx.x;
#pragma unroll
  for (int i = 0; i < 4; ++i) {
    const int c = i * 512 + t;            // 16B chunk 0..2047
    const int r = c >> 3;                 // row 0..255
    const int l = (c & 7) ^ (r & 7);      // logical slot for linear dest
    gload16(dst + (size_t)c * 8, src + (size_t)r * K + k0 + l * 8);
  }
}

__device__ __forceinline__ void gemm256_core(const bf16* __restrict__ Ab,
                                             const bf16* __restrict__ Bb,
                                             int K, f32x4 acc[8][4]) {
  __shared__ alignas(16) bf16 lds[2][2][256 * 64];  // [buf][0=A,1=B], 128 KiB
  const int lane = threadIdx.x & 63;
  const int wid  = threadIdx.x >> 6;
  const int wr   = wid >> 2, wc = wid & 3;
  const int lr   = lane & 15;
  const int kg   = lane >> 4;             // 16B slot sub-index 0..3

#pragma unroll
  for (int m = 0; m < 8; ++m)
#pragma unroll
    for (int n = 0; n < 4; ++n)
      acc[m][n] = f32x4{0.f, 0.f, 0.f, 0.f};

  const int NT = K >> 6;
  // prologue: B first, then A; seal B; barrier globalizes
  stage_mat(lds[0][1], Bb, K, 0);
  stage_mat(lds[0][0], Ab, K, 0);
  asm volatile("s_waitcnt vmcnt(4)" ::: "memory");   // retires B(0); A(0) flies
  BAR();

  bf16x8 fb[4][2];   // all B frags (n=0..3, ks=0..1) — live whole tile
  bf16x8 fa[4][2];   // current A m-half

  for (int t = 0; t < NT; ++t) {
    const bf16* pA = lds[t & 1][0];
    const bf16* pB = lds[t & 1][1];
    bf16* nA = lds[(t + 1) & 1][0];
    bf16* nB = lds[(t + 1) & 1][1];

    // ---------------- p0: (mh0, nh0) ----------------
    if (t + 1 < NT) {
      stage_mat(nB, Bb, K, (t + 1) << 6);
      asm volatile("s_waitcnt vmcnt(4)" ::: "memory");  // retires A(t)
    } else {
      asm volatile("s_waitcnt vmcnt(0)" ::: "memory");  // tail: drain A(t)
    }
    // pre-reads: all B frags of tile t (sealed at previous p3 barrier)
#pragma unroll
    for (int n = 0; n < 4; ++n) {
      const int r = wc * 64 + n * 16 + lr;
#pragma unroll
      for (int ks = 0; ks < 2; ++ks)
        fb[n][ks] = *(const bf16x8*)&pB[r * 64 + ((((ks << 2) + kg) ^ (r & 7)) << 3)];
    }
    BAR();  // globalizes A(t) seal
    // post-barrier reads: A mh0
#pragma unroll
    for (int m = 0; m < 4; ++m) {
      const int r = wr * 128 + m * 16 + lr;
#pragma unroll
      for (int ks = 0; ks < 2; ++ks)
        fa[m][ks] = *(const bf16x8*)&pA[r * 64 + ((((ks << 2) + kg) ^ (r & 7)) << 3)];
    }
    __builtin_amdgcn_s_setprio(1);
#pragma unroll
    for (int m = 0; m < 4; ++m)
#pragma unroll
      for (int n = 0; n < 2; ++n)
#pragma unroll
        for (int ks = 0; ks < 2; ++ks)
          acc[m][n] = __builtin_amdgcn_mfma_f32_16x16x32_bf16(fa[m][ks], fb[n][ks], acc[m][n], 0, 0, 0);
    __builtin_amdgcn_s_setprio(0);

    // ---------------- p1: (mh0, nh1) ----------------
    if (t + 1 < NT) stage_mat(nA, Ab, K, (t + 1) << 6);
    BAR();
    __builtin_amdgcn_s_setprio(1);
#pragma unroll
    for (int m = 0; m < 4; ++m)
#pragma unroll
      for (int n = 0; n < 2; ++n)
#pragma unroll
        for (int ks = 0; ks < 2; ++ks)
          acc[m][n + 2] = __builtin_amdgcn_mfma_f32_16x16x32_bf16(fa[m][ks], fb[n + 2][ks], acc[m][n + 2], 0, 0, 0);
    __builtin_amdgcn_s_setprio(0);

    // ---------------- p2: (mh1, nh0) ----------------
    // pre-reads: A mh1 (sealed at this tile's p0 barrier)
#pragma unroll
    for (int m = 0; m < 4; ++m) {
      const int r = wr * 128 + (m + 4) * 16 + lr;
#pragma unroll
      for (int ks = 0; ks < 2; ++ks)
        fa[m][ks] = *(const bf16x8*)&pA[r * 64 + ((((ks << 2) + kg) ^ (r & 7)) << 3)];
    }
    BAR();
    __builtin_amdgcn_s_setprio(1);
#pragma unroll
    for (int m = 0; m < 4; ++m)
#pragma unroll
      for (int n = 0; n < 2; ++n)
#pragma unroll
        for (int ks = 0; ks < 2; ++ks)
          acc[m + 4][n] = __builtin_amdgcn_mfma_f32_16x16x32_bf16(fa[m][ks], fb[n][ks], acc[m + 4][n], 0, 0, 0);
    __builtin_amdgcn_s_setprio(0);

    // ---------------- p3: (mh1, nh1) ----------------
    if (t + 1 < NT)
      asm volatile("s_waitcnt vmcnt(4)" ::: "memory");  // retires B(t+1)
    BAR();  // globalizes B(t+1) seal — its pre-reads happen at t+1.p0
    __builtin_amdgcn_s_setprio(1);
#pragma unroll
    for (int m = 0; m < 4; ++m)
#pragma unroll
      for (int n = 0; n < 2; ++n)
#pragma unroll
        for (int ks = 0; ks < 2; ++ks)
          acc[m + 4][n + 2] = __builtin_amdgcn_mfma_f32_16x16x32_bf16(fa[m][ks], fb[n + 2][ks], acc[m + 4][n + 2], 0, 0, 0);
    __builtin_amdgcn_s_setprio(0);
  }
}

// C/D mapping within the wave's 128x64 subtile:
//   row = wr*128 + m*16 + (lane>>4)*4 + j ; col = wc*64 + n*16 + (lane&15)

// ---------------- conversion / transpose ----------------

__global__ __launch_bounds__(256)
void k_cvt(const float* __restrict__ in, bf16* __restrict__ out, int n8) {
  const int i = blockIdx.x * 256 + threadIdx.x;
  if (i >= n8) return;
  const float* p = in + (size_t)i * 8;
  bf16x8 o;
#pragma unroll
  for (int j = 0; j < 8; ++j) o[j] = (bf16)p[j];
  *(bf16x8*)(out + (size_t)i * 8) = o;
}

// in: R x C fp32 (row-major) -> out: C x R bf16
__global__ __launch_bounds__(256)
void k_transpose(const float* __restrict__ in, bf16* __restrict__ out, int R, int C) {
  __shared__ float tile[64][65];
  const int r0 = blockIdx.y * 64, c0 = blockIdx.x * 64;
  const int t = threadIdx.x;
#pragma unroll
  for (int i = 0; i < 16; ++i) {
    const int flat = i * 256 + t;
    const int r = flat >> 6, c = flat & 63;
    tile[r][c] = in[(size_t)(r0 + r) * C + (c0 + c)];
  }
  __syncthreads();
#pragma unroll
  for (int i = 0; i < 16; ++i) {
    const int flat = i * 256 + t;
    const int r = flat >> 6, c = flat & 63;
    out[(size_t)(c0 + r) * R + (r0 + c)] = (bf16)tile[c][r];
  }
}

// In-place per-batch transpose of a SEQ x SEQ bf16 matrix (tile-pair swap).
__global__ __launch_bounds__(256)
void k_vtrans(bf16* __restrict__ a) {
  const int bi = blockIdx.y, bj = blockIdx.x;
  if (bj < bi) return;
  bf16* A = a + (size_t)blockIdx.z * SEQ * SEQ;
  __shared__ float t0[64][65];
  __shared__ float t1[64][65];
  const int r0 = bi * 64, c0 = bj * 64;
  const int t = threadIdx.x;
  const bool diag = (bi == bj);
#pragma unroll
  for (int i = 0; i < 16; ++i) {
    const int flat = i * 256 + t;
    const int r = flat >> 6, c = flat & 63;
    t0[r][c] = (float)A[(size_t)(r0 + r) * SEQ + (c0 + c)];
    if (!diag) t1[r][c] = (float)A[(size_t)(c0 + r) * SEQ + (r0 + c)];
  }
  __syncthreads();
#pragma unroll
  for (int i = 0; i < 16; ++i) {
    const int flat = i * 256 + t;
    const int r = flat >> 6, c = flat & 63;
    A[(size_t)(r0 + r) * SEQ + (c0 + c)] = (bf16)(diag ? t0[c][r] : t1[c][r]);
    if (!diag) A[(size_t)(c0 + r) * SEQ + (r0 + c)] = (bf16)t0[c][r];
  }
}

// ---------------- GEMM1: h = x@W_i + b_i ; SiLU ; split u/v/q/k ----------------

__global__ __launch_bounds__(512, 2)
void k_gemm1(const bf16* __restrict__ xb, const bf16* __restrict__ wibt,
             const float* __restrict__ b_i,
             const float* __restrict__ q_w, const float* __restrict__ q_b,
             const float* __restrict__ k_w, const float* __restrict__ k_b,
             bf16* __restrict__ u, bf16* __restrict__ v,
             bf16* __restrict__ q, bf16* __restrict__ k) {
  int wg = blockIdx.x;                       // 1088 = 64 x 17
  wg = (wg & 7) * 136 + (wg >> 3);           // XCD swizzle (bijective)
  const int bm0 = (wg / 17) * 256;
  const int bn0 = (wg % 17) * 256;
  f32x4 acc[8][4];
  gemm256_core(xb + (size_t)bm0 * DM, wibt + (size_t)bn0 * DM, DM, acc);
  const int lane = threadIdx.x & 63;
  const int wid  = threadIdx.x >> 6;
  const int wr = wid >> 2, wc = wid & 3;
  const float rs = 0.08838834764831845f;     // 1/sqrt(128)
#pragma unroll
  for (int m = 0; m < 8; ++m)
#pragma unroll
    for (int n = 0; n < 4; ++n)
#pragma unroll
      for (int j = 0; j < 4; ++j) {
        const int row = bm0 + wr * 128 + m * 16 + ((lane >> 4) << 2) + j;
        const int col = bn0 + wc * 64 + n * 16 + (lane & 15);
        if (col >= NH) continue;
        const float h = acc[m][n][j] + b_i[col];
        const float s = h / (1.f + __expf(-h));  // silu
        if (col < VG) {
          u[(size_t)row * VG + col] = (bf16)s;
        } else if (col < 2 * VG) {
          v[(size_t)row * VG + (col - VG)] = (bf16)s;
        } else {
          const int c = col - 2 * VG;
          q[(size_t)row * QKD + c] = (bf16)((s * q_w[c] + q_b[c]) * rs);
          k[(size_t)row * QKD + c] = (bf16)(s * k_w[c] + k_b[c]);
        }
      }
}

// ---------------- S-chunk = q[m0:m0+CH] @ k^T (per batch) ----------------

__global__ __launch_bounds__(512, 2)
void k_gemmS(const bf16* __restrict__ q, const bf16* __restrict__ k,
             bf16* __restrict__ P, int m0) {
  int wg = blockIdx.x;                       // 256 = 8b x 4m x 8n
  wg = (wg & 7) * 32 + (wg >> 3);
  const int b   = wg >> 5;
  const int bm0 = ((wg >> 3) & 3) * 256;
  const int bn0 = (wg & 7) * 256;
  f32x4 acc[8][4];
  gemm256_core(q + ((size_t)b * SEQ + m0 + bm0) * QKD,
               k + ((size_t)b * SEQ + bn0) * QKD, QKD, acc);
  bf16* Pb = P + (size_t)b * CH * SEQ;
  const int lane = threadIdx.x & 63;
  const int wid  = threadIdx.x >> 6;
  const int wr = wid >> 2, wc = wid & 3;
#pragma unroll
  for (int m = 0; m < 8; ++m)
#pragma unroll
    for (int n = 0; n < 4; ++n)
#pragma unroll
      for (int j = 0; j < 4; ++j) {
        const int row = bm0 + wr * 128 + m * 16 + ((lane >> 4) << 2) + j;
        const int col = bn0 + wc * 64 + n * 16 + (lane & 15);
        Pb[(size_t)row * SEQ + col] = (bf16)acc[m][n][j];
      }
}

// ---------------- row softmax over chunk (in place), key padding mask ----------------

__global__ __launch_bounds__(256)
void k_softmax(bf16* __restrict__ P, const int* __restrict__ mask) {
  const int row = blockIdx.x;       // 0..NB*CH-1
  const int b = row >> 10;          // row / CH
  const int t = threadIdx.x;
  bf16* srow = P + (size_t)row * SEQ;
  const int* mrow = mask + (size_t)b * SEQ;
  bf16x8 vv = *(const bf16x8*)(srow + t * 8);
  float f[8];
  float mx = -1e30f;
#pragma unroll
  for (int j = 0; j < 8; ++j) {
    const bool ok = mrow[t * 8 + j] != 0;
    f[j] = ok ? (float)vv[j] : -1e30f;
    mx = fmaxf(mx, f[j]);
  }
#pragma unroll
  for (int off = 32; off > 0; off >>= 1) mx = fmaxf(mx, __shfl_xor(mx, off));
  __shared__ float redm[4], reds[4];
  if ((t & 63) == 0) redm[t >> 6] = mx;
  __syncthreads();
  mx = fmaxf(fmaxf(redm[0], redm[1]), fmaxf(redm[2], redm[3]));
  float sum = 0.f;
#pragma unroll
  for (int j = 0; j < 8; ++j) {
    f[j] = (f[j] > -1e29f) ? __expf(f[j] - mx) : 0.f;
    sum += f[j];
  }
#pragma unroll
  for (int off = 32; off > 0; off >>= 1) sum += __shfl_xor(sum, off);
  if ((t & 63) == 0) reds[t >> 6] = sum;
  __syncthreads();
  sum = reds[0] + reds[1] + reds[2] + reds[3];
  const float inv = 1.f / sum;
#pragma unroll
  for (int j = 0; j < 8; ++j) vv[j] = (bf16)(f[j] * inv);
  *(bf16x8*)(srow + t * 8) = vv;
}

// ---------------- o = u .* (P @ v), written over u in place ----------------

__global__ __launch_bounds__(512, 2)
void k_gemmO(const bf16* __restrict__ P, const bf16* __restrict__ vT,
             bf16* uo, int m0) {
  int wg = blockIdx.x;                       // 256 = 8b x 4m x 8n
  wg = (wg & 7) * 32 + (wg >> 3);
  const int b   = wg >> 5;
  const int bm0 = ((wg >> 3) & 3) * 256;
  const int bn0 = (wg & 7) * 256;
  f32x4 acc[8][4];
  gemm256_core(P + ((size_t)b * CH + bm0) * SEQ,
               vT + ((size_t)b * VG + bn0) * SEQ, SEQ, acc);
  const int lane = threadIdx.x & 63;
  const int wid  = threadIdx.x >> 6;
  const int wr = wid >> 2, wc = wid & 3;
#pragma unroll
  for (int m = 0; m < 8; ++m)
#pragma unroll
    for (int n = 0; n < 4; ++n)
#pragma unroll
      for (int j = 0; j < 4; ++j) {
        const int row = bm0 + wr * 128 + m * 16 + ((lane >> 4) << 2) + j;
        const int col = bn0 + wc * 64 + n * 16 + (lane & 15);
        const size_t idx = ((size_t)(b * SEQ + m0 + row)) * VG + col;
        uo[idx] = (bf16)(acc[m][n][j] * (float)uo[idx]);
      }
}

// ---------------- out = o @ W_o + b_o (fp32 out) ----------------

__global__ __launch_bounds__(512, 2)
void k_gemm2(const bf16* __restrict__ o, const bf16* __restrict__ wobt,
             const float* __restrict__ b_o, float* __restrict__ out) {
  int wg = blockIdx.x;                       // 256 = 64m x 4n
  wg = (wg & 7) * 32 + (wg >> 3);
  const int bm0 = (wg >> 2) * 256;
  const int bn0 = (wg & 3) * 256;
  f32x4 acc[8][4];
  gemm256_core(o + (size_t)bm0 * VG, wobt + (size_t)bn0 * VG, VG, acc);
  const int lane = threadIdx.x & 63;
  const int wid  = threadIdx.x >> 6;
  const int wr = wid >> 2, wc = wid & 3;
#pragma unroll
  for (int m = 0; m < 8; ++m)
#pragma unroll
    for (int n = 0; n < 4; ++n)
#pragma unroll
      for (int j = 0; j < 4; ++j) {
        const int row = bm0 + wr * 128 + m * 16 + ((lane >> 4) << 2) + j;
        const int col = bn0 + wc * 64 + n * 16 + (lane & 15);
        out[(size_t)row * DM + col] = acc[m][n][j] + b_o[col];
      }
}

// ---------------- launch ----------------
// Workspace (189.4 MB): wobt 4.2 | xb/P 33.6 | wibt(pad) 8.9 | qb 4.2
//                       | kb 4.2 | uo 67.1 | v 67.1

extern "C" void kernel_launch(void* const* d_in, const int* in_sizes, int n_in,
                              void* d_out, int out_size, void* d_ws, size_t ws_size,
                              hipStream_t stream) {
  const float* x   = (const float*)d_in[0];
  const int*   pm  = (const int*)d_in[1];
  const float* W_i = (const float*)d_in[2];
  const float* b_i = (const float*)d_in[3];
  const float* q_w = (const float*)d_in[4];
  const float* q_b = (const float*)d_in[5];
  const float* k_w = (const float*)d_in[6];
  const float* k_b = (const float*)d_in[7];
  const float* W_o = (const float*)d_in[8];
  const float* b_o = (const float*)d_in[9];
  float* out = (float*)d_out;

  char* w = (char*)d_ws;
  bf16* wobt = (bf16*)w; w += (size_t)DM * VG * 2;
  bf16* xb   = (bf16*)w; w += (size_t)MTOT * DM * 2;   // reused as P chunk
  bf16* wibt = (bf16*)w; w += (size_t)NHP * DM * 2;    // padded to 4352 rows
  bf16* qb   = (bf16*)w; w += (size_t)MTOT * QKD * 2;
  bf16* kb   = (bf16*)w; w += (size_t)MTOT * QKD * 2;
  bf16* uo   = (bf16*)w; w += (size_t)MTOT * VG * 2;   // u, then o (in place)
  bf16* vb   = (bf16*)w; w += (size_t)MTOT * VG * 2;   // v, then vT (in place)
  bf16* Pc   = xb;

  // x -> bf16
  k_cvt<<<dim3(MTOT * DM / 8 / 256), 256, 0, stream>>>(x, xb, MTOT * DM / 8);
  // W_i (DM x NH) -> (NH x DM) bf16, pad rows [NH, NHP) zeroed
  hipMemsetAsync(wibt + (size_t)NH * DM, 0, (size_t)(NHP - NH) * DM * 2, stream);
  k_transpose<<<dim3(NH / 64, DM / 64), 256, 0, stream>>>(W_i, wibt, DM, NH);
  // W_o (VG x DM) -> (DM x VG) bf16
  k_transpose<<<dim3(DM / 64, VG / 64), 256, 0, stream>>>(W_o, wobt, VG, DM);
  // GEMM1 + silu + split (xb dead afterwards)
  k_gemm1<<<dim3(64 * 17), 512, 0, stream>>>(
      xb, wibt, b_i, q_w, q_b, k_w, k_b, uo, vb, qb, kb);
  // v -> v^T in place (square per batch)
  k_vtrans<<<dim3(SEQ / 64, SEQ / 64, NB), 256, 0, stream>>>(vb);
  // attention in CH-row chunks; P overlays xb
  for (int c = 0; c < SEQ / CH; ++c) {
    const int m0 = c * CH;
    k_gemmS<<<dim3(NB * 4 * 8), 512, 0, stream>>>(qb, kb, Pc, m0);
    k_softmax<<<dim3(NB * CH), 256, 0, stream>>>(Pc, pm);
    k_gemmO<<<dim3(NB * 4 * 8), 512, 0, stream>>>(Pc, vb, uo, m0);
  }
  // out = o @ W_o + b_o
  k_gemm2<<<dim3(64 * 4), 512, 0, stream>>>(uo, wobt, b_o, out);
}